// Round 1
// 398.438 us; speedup vs baseline: 1.0046x; 1.0046x over previous
//
#include <hip/hip_runtime.h>
#include <hip/hip_bf16.h>
#include <hip/hip_fp16.h>
#include <math.h>

typedef _Float16 half8 __attribute__((ext_vector_type(8)));
typedef __attribute__((ext_vector_type(4))) float floatx4;

constexpr int Bc = 2, Rc = 16, Cc = 512, Ec = 1024, Hc = 16, Dc = 64;
// fold 1/sqrt(64) * log2(e) into Q so softmax uses exp2 (v_exp_f32 native)
#define QSCALE 0.180336880111120425f

__device__ inline void gl_lds16(const void* g, void* l) {
  __builtin_amdgcn_global_load_lds(
      (const __attribute__((address_space(1))) void*)g,
      (__attribute__((address_space(3))) void*)l, 16, 0, 0);
}
__device__ inline unsigned short f2h(float f) {
  __half h = __float2half_rn(f);
  return *(unsigned short*)&h;
}
__device__ inline unsigned int pack_h2(float lo, float hi) {
  __half2 p = __float22half2_rn(make_float2(lo, hi));
  return *(unsigned int*)&p;
}

// ---------- x fp32 -> fp16 ----------
__global__ __launch_bounds__(256) void cvt_x(const float* __restrict__ x,
                                             unsigned short* __restrict__ xh) {
  const size_t base = ((size_t)blockIdx.x * 256 + threadIdx.x) * 8;
  float4 a = *(const float4*)(x + base);
  float4 b = *(const float4*)(x + base + 4);
  uint4 o;
  o.x = pack_h2(a.x, a.y);
  o.y = pack_h2(a.z, a.w);
  o.z = pack_h2(b.x, b.y);
  o.w = pack_h2(b.z, b.w);
  *(uint4*)(xh + base) = o;
}

// ---------- W[k][n] fp32 -> Wt[n][k] fp16 (transpose), z picks weight ------
__global__ __launch_bounds__(256) void wprep(
    const float* __restrict__ w0, const float* __restrict__ w1,
    const float* __restrict__ w2, const float* __restrict__ w3,
    unsigned short* __restrict__ t0, unsigned short* __restrict__ t1,
    unsigned short* __restrict__ t2, unsigned short* __restrict__ t3) {
  __shared__ float tile[64][65];
  const int z = blockIdx.z;
  const float* W = (z == 0) ? w0 : (z == 1) ? w1 : (z == 2) ? w2 : w3;
  unsigned short* T = (z == 0) ? t0 : (z == 1) ? t1 : (z == 2) ? t2 : t3;
  const int tid = threadIdx.x;
  const int bk = blockIdx.x * 64, bn = blockIdx.y * 64;
#pragma unroll
  for (int p = 0; p < 16; ++p) {
    int idx = p * 256 + tid;
    int lk = idx >> 6, ln = idx & 63;
    tile[ln][lk] = W[(size_t)(bk + lk) * 1024 + bn + ln];
  }
  __syncthreads();
#pragma unroll
  for (int p = 0; p < 16; ++p) {
    int idx = p * 256 + tid;
    int ln = idx >> 6, lk = idx & 63;
    T[(size_t)(bn + ln) * 1024 + bk + lk] = f2h(tile[ln][lk]);
  }
}

// ===========================================================================
// 256x256 BK=64 double-buffered 4-phase GEMM with counted vmcnt (T2+T3+T4+T5)
// MODE 0: fused QKV (N=3072, contiguous wq|wk|wv transposed weights), per-z
//         epilogue (Q scaled [c][d], K [c][d], V^T [d][c]).
// MODE 1: output GEMM, fp32 [m][1024] + bias.
// LDS swizzle: chunk ^= (row&7) on 128B rows, imposed by inverse-permuted
// global source (linear gl_lds dest), un-done at ds_read. 2-way banks = free.
// Schedule per K-tile T (buf b=T&1), stages into the *other* tile's regions
// only after their last-read phase barrier:
//   P1: read A[m0]+B[n0]; stage (T+1).A1,(T+1).B0   -> barrier,lgkm0,16 MFMA
//   P2: read B[n1];       stage (T+1).B1
//   P3: read A[m1]
//   P4: read B[n0];       stage (T+2).A0; vmcnt(2)  (never 0 mid-loop)
// vmcnt(2) at P4 guarantees tile T+1 fully staged (only (T+2).A0 in flight).
// ===========================================================================
#define STG(OP, BUF, KT, H)                                                   \
  {                                                                           \
    const unsigned short* gsp_ = (OP) ? Bb : Ab;                              \
    unsigned short* lb_ =                                                     \
        ((OP) ? Bs : As) + (BUF) * 16384 + (H) * 8192 + w * 1024;             \
    _Pragma("unroll") for (int l_ = 0; l_ < 2; ++l_)                          \
        gl_lds16(gsp_ + (size_t)((H) * 128 + srow + l_ * 8) * 1024 +          \
                     (KT) * 64 + goff,                                        \
                 lb_ + l_ * 512);                                             \
  }

#define DSRA(BUF, MH)                                                         \
  _Pragma("unroll") for (int i_ = 0; i_ < 4; ++i_) {                          \
    const unsigned short* p_ =                                                \
        As + (BUF) * 16384 + (wm + (MH) * 64 + i_ * 16 + lr) * 64;            \
    af[i_][0] = *(const half8*)(p_ + sw0);                                    \
    af[i_][1] = *(const half8*)(p_ + sw1);                                    \
  }

#define DSRB(BUF, NH)                                                         \
  _Pragma("unroll") for (int j_ = 0; j_ < 2; ++j_) {                          \
    const unsigned short* p_ =                                                \
        Bs + (BUF) * 16384 + (wn + (NH) * 32 + j_ * 16 + lr) * 64;            \
    bf[j_][0] = *(const half8*)(p_ + sw0);                                    \
    bf[j_][1] = *(const half8*)(p_ + sw1);                                    \
  }

#define MFMA16(MH, NH)                                                        \
  _Pragma("unroll") for (int i_ = 0; i_ < 4; ++i_)                            \
      _Pragma("unroll") for (int j_ = 0; j_ < 2; ++j_) {                      \
    acc[(MH)*4 + i_][(NH)*2 + j_] = __builtin_amdgcn_mfma_f32_16x16x32_f16(   \
        af[i_][0], bf[j_][0], acc[(MH)*4 + i_][(NH)*2 + j_], 0, 0, 0);        \
    acc[(MH)*4 + i_][(NH)*2 + j_] = __builtin_amdgcn_mfma_f32_16x16x32_f16(   \
        af[i_][1], bf[j_][1], acc[(MH)*4 + i_][(NH)*2 + j_], 0, 0, 0);        \
  }

#define WAIT_LGKM0                                                            \
  {                                                                           \
    asm volatile("s_waitcnt lgkmcnt(0)" ::: "memory");                        \
    __builtin_amdgcn_sched_barrier(0);                                        \
  }
#define WAIT_VM(N)                                                            \
  {                                                                           \
    asm volatile("s_waitcnt vmcnt(" #N ")" ::: "memory");                     \
    __builtin_amdgcn_sched_barrier(0);                                        \
  }

#define TILE(T, BUF, S12, S4, VM0)                                            \
  {                                                                           \
    /* P1 */                                                                  \
    DSRA(BUF, 0);                                                             \
    DSRB(BUF, 0);                                                             \
    if (S12) {                                                                \
      STG(0, (BUF) ^ 1, (T) + 1, 1);                                          \
      STG(1, (BUF) ^ 1, (T) + 1, 0);                                          \
    }                                                                         \
    __builtin_amdgcn_s_barrier();                                             \
    WAIT_LGKM0;                                                               \
    __builtin_amdgcn_s_setprio(1);                                            \
    MFMA16(0, 0);                                                             \
    __builtin_amdgcn_s_setprio(0);                                            \
    __builtin_amdgcn_s_barrier();                                             \
    __builtin_amdgcn_sched_barrier(0);                                        \
    /* P2 */                                                                  \
    DSRB(BUF, 1);                                                             \
    if (S12) { STG(1, (BUF) ^ 1, (T) + 1, 1); }                               \
    __builtin_amdgcn_s_barrier();                                             \
    WAIT_LGKM0;                                                               \
    __builtin_amdgcn_s_setprio(1);                                            \
    MFMA16(0, 1);                                                             \
    __builtin_amdgcn_s_setprio(0);                                            \
    __builtin_amdgcn_s_barrier();                                             \
    __builtin_amdgcn_sched_barrier(0);                                        \
    /* P3 */                                                                  \
    DSRA(BUF, 1);                                                             \
    __builtin_amdgcn_s_barrier();                                             \
    WAIT_LGKM0;                                                               \
    __builtin_amdgcn_s_setprio(1);                                            \
    MFMA16(1, 1);                                                             \
    __builtin_amdgcn_s_setprio(0);                                            \
    __builtin_amdgcn_s_barrier();                                             \
    __builtin_amdgcn_sched_barrier(0);                                        \
    /* P4 */                                                                  \
    DSRB(BUF, 0);                                                             \
    if (S4) { STG(0, BUF, (T) + 2, 0); }                                      \
    if (VM0) { WAIT_VM(0); } else { WAIT_VM(2); }                             \
    __builtin_amdgcn_s_barrier();                                             \
    WAIT_LGKM0;                                                               \
    __builtin_amdgcn_s_setprio(1);                                            \
    MFMA16(1, 0);                                                             \
    __builtin_amdgcn_s_setprio(0);                                            \
    __builtin_amdgcn_s_barrier();                                             \
    __builtin_amdgcn_sched_barrier(0);                                        \
  }

template <int MODE>
__global__ __launch_bounds__(512, 2) void gemm256(
    const unsigned short* __restrict__ gA, const unsigned short* __restrict__ gB,
    const float* __restrict__ bq, const float* __restrict__ bk,
    const float* __restrict__ bv, unsigned short* __restrict__ qout,
    unsigned short* __restrict__ kout, unsigned short* __restrict__ vout,
    float* __restrict__ fout, const float* __restrict__ bo) {
  __shared__ unsigned short As[2 * 16384];  // 64 KB (2 buf x 256 x 64)
  __shared__ unsigned short Bs[2 * 16384];  // 64 KB
  const int tid = threadIdx.x;
  const int w = tid >> 6, ln = tid & 63;
  const int lr = ln & 15, quad = ln >> 4;
  const int wm = (w >> 2) * 128, wn = (w & 3) * 64;
  int bm, bn;
  if (MODE == 0) {
    const int swz = (blockIdx.x & 7) * 96 + (blockIdx.x >> 3);  // 768 wgs
    bm = (swz / 12) * 256;
    bn = (swz % 12) * 256;
  } else {
    const int swz = (blockIdx.x & 7) * 32 + (blockIdx.x >> 3);  // 256 wgs
    bm = (swz >> 2) * 256;
    bn = (swz & 3) * 256;
  }
  const unsigned short* Ab = gA + (size_t)bm * 1024;
  const unsigned short* Bb = gB + (size_t)bn * 1024;
  // per-lane staging offset: row = base + (ln>>3), src chunk = (ln&7)^(ln>>3)
  const int goff = (ln >> 3) * 1024 + (((ln & 7) ^ (ln >> 3)) << 3);
  const int srow = w * 16;
  // ds_read swizzled chunk offsets (halves): chunk = (kk*4|quad) ^ (row&7),
  // row&7 == lr&7 for all frag rows.
  const int sw0 = ((quad ^ (lr & 7)) << 3);
  const int sw1 = (((4 | quad) ^ (lr & 7)) << 3);

  floatx4 acc[8][4];
#pragma unroll
  for (int i = 0; i < 8; ++i)
#pragma unroll
    for (int j = 0; j < 4; ++j) acc[i][j] = (floatx4)(0.f);
  half8 af[4][2], bf[2][2];

  // prologue: tile0 fully + tile1.A0; wait all but the last half-tile
  STG(0, 0, 0, 0);
  STG(0, 0, 0, 1);
  STG(1, 0, 0, 0);
  STG(1, 0, 0, 1);
  STG(0, 1, 1, 0);
  WAIT_VM(2);
  __builtin_amdgcn_s_barrier();
  __builtin_amdgcn_sched_barrier(0);

  for (int t = 0; t < 7; ++t) {  // tiles 0..13 steady
    const int T0 = 2 * t;
    TILE(T0, 0, 1, 1, 0);
    TILE(T0 + 1, 1, 1, 1, 0);
  }
  TILE(14, 0, 1, 0, 1);  // stages tile15 A1/B0/B1, drains
  TILE(15, 1, 0, 0, 1);  // no stages

  // ----- epilogue -----
  const int q4 = quad * 4;
  const bool odd = ln & 1;
  if constexpr (MODE == 0) {
    const int z = bn >> 10;  // block-uniform (BN=256 divides 1024)
    const float* bias = (z == 0) ? bq : (z == 1) ? bk : bv;
    const int czb = (bn & 1023) + wn;
#pragma unroll
    for (int i = 0; i < 8; ++i) {
#pragma unroll
      for (int j = 0; j < 4; ++j) {
        const int colz = czb + j * 16 + lr;
        float v[4];
#pragma unroll
        for (int r = 0; r < 4; ++r) v[r] = acc[i][j][r] + bias[colz];
        const int m0 = bm + wm + i * 16 + q4;
        const int h = colz >> 6, d = colz & 63;
        const int brr = m0 >> 9, c0 = m0 & 511;
        const size_t hb = ((size_t)brr * 16 + h) * 32768;
        if (z == 2) {
          // V^T [d][c]: 4 consecutive c per thread -> one 8B store
          uint2 o;
          o.x = pack_h2(v[0], v[1]);
          o.y = pack_h2(v[2], v[3]);
          *(uint2*)(vout + hb + (size_t)d * 512 + c0) = o;
        } else {
          unsigned short* outp = (z == 0) ? qout : kout;
          if (z == 0) {
#pragma unroll
            for (int r = 0; r < 4; ++r) v[r] *= QSCALE;
          }
          // [c][d]: lane-pair exchange -> 4B stores
#pragma unroll
          for (int rp = 0; rp < 2; ++rp) {
            float a = v[2 * rp], b = v[2 * rp + 1];
            float ax = __shfl_xor(a, 1), bx = __shfl_xor(b, 1);
            unsigned int u = odd ? pack_h2(bx, b) : pack_h2(a, ax);
            const int c = c0 + 2 * rp + (odd ? 1 : 0);
            const int dd = d & ~1;
            *(unsigned int*)(outp + hb + (size_t)c * 64 + dd) = u;
          }
        }
      }
    }
  } else {
#pragma unroll
    for (int i = 0; i < 8; ++i)
#pragma unroll
      for (int j = 0; j < 4; ++j) {
        const int col = bn + wn + j * 16 + lr;
#pragma unroll
        for (int r = 0; r < 4; ++r) {
          const int m = bm + wm + i * 16 + q4 + r;
          fout[(size_t)m * 1024 + col] = acc[i][j][r] + bo[col];
        }
      }
  }
}

// ---------- MFMA flash attention, fp16 (no-max softmax: logits small) ------
// Q fp16 [bh][c][d] (pre-scaled); K fp16 [bh][c][d]; Vt fp16 [bh][d][c].
// Out: ctx fp16 [m][e]. 256 thr, one (bh, 128q tile); wave owns 32 q.
__global__ __launch_bounds__(256, 2) void attn_mfma(
    const unsigned short* __restrict__ Qh, const unsigned short* __restrict__ Kb,
    const unsigned short* __restrict__ Vt, unsigned short* __restrict__ Ctx) {
  __shared__ unsigned short Ks[128 * 64];   // [k][d], slot-swizzle c16^=(k&7)
  __shared__ unsigned short Vs[64 * 128];   // [d][k], slot-swizzle c16^=(d&15)
  __shared__ unsigned short Ps[128][136];   // [q][k] fp16, +8 pad

  const int t = threadIdx.x;
  const int w = t >> 6, ln = t & 63;
  const int lane15 = ln & 15, quad = ln >> 4;
  const bool odd = ln & 1;
  const int bh = blockIdx.x >> 2;
  const int qb = (blockIdx.x & 3) * 128;

  half8 qf[2][2];
  {
    const size_t qbase =
        ((size_t)bh * 512 + qb + w * 32 + lane15) * 64 + quad * 8;
#pragma unroll
    for (int i = 0; i < 2; ++i)
#pragma unroll
      for (int c = 0; c < 2; ++c)
        qf[i][c] = *(const half8*)(Qh + qbase + (size_t)i * 16 * 64 + c * 32);
  }

  floatx4 oacc[2][4];
#pragma unroll
  for (int i = 0; i < 2; ++i)
#pragma unroll
    for (int dj = 0; dj < 4; ++dj) oacc[i][dj] = (floatx4)(0.f);
  float lsum[2][4];
#pragma unroll
  for (int i = 0; i < 2; ++i)
#pragma unroll
    for (int r = 0; r < 4; ++r) lsum[i][r] = 0.f;

  const unsigned short* kgb = Kb + (size_t)bh * 32768;
  const unsigned short* vgb = Vt + (size_t)bh * 32768;

  for (int kt = 0; kt < 512; kt += 128) {
    __syncthreads();
    {
      const unsigned short* kq = kgb + (size_t)kt * 64;
#pragma unroll
      for (int p = 0; p < 4; ++p) {
        const int s = p * 256 + t;
        const int kr = s >> 3, kc16 = s & 7;
        gl_lds16(kq + kr * 64 + ((kc16 ^ (kr & 7)) << 3), (char*)Ks + s * 16);
        const int vr = s >> 4, vc16 = s & 15;
        gl_lds16(vgb + vr * 512 + kt + ((vc16 ^ (vr & 15)) << 3),
                 (char*)Vs + s * 16);
      }
    }
    __syncthreads();

    // ---- S = Q K^T ----
    floatx4 sacc[2][8];
#pragma unroll
    for (int i = 0; i < 2; ++i)
#pragma unroll
      for (int j = 0; j < 8; ++j) sacc[i][j] = (floatx4)(0.f);
#pragma unroll
    for (int j = 0; j < 8; ++j) {
      const int krow = j * 16 + lane15;
      const unsigned short* kr = Ks + krow * 64;
      half8 kf0 = *(const half8*)(kr + ((quad ^ (krow & 7)) << 3));
      half8 kf1 = *(const half8*)(kr + (((4 + quad) ^ (krow & 7)) << 3));
#pragma unroll
      for (int i = 0; i < 2; ++i) {
        sacc[i][j] = __builtin_amdgcn_mfma_f32_16x16x32_f16(qf[i][0], kf0,
                                                            sacc[i][j], 0, 0, 0);
        sacc[i][j] = __builtin_amdgcn_mfma_f32_16x16x32_f16(qf[i][1], kf1,
                                                            sacc[i][j], 0, 0, 0);
      }
    }

    // ---- P = exp2(S) (no max-sub: |S| small), pack pairs, write P[q][k] ---
#pragma unroll
    for (int i = 0; i < 2; ++i) {
#pragma unroll
      for (int rp = 0; rp < 2; ++rp) {
        const int rA = rp * 2, rB = rA + 1;
        const int row = w * 32 + i * 16 + quad * 4 + rA + (odd ? 1 : 0);
        unsigned short* prow = &Ps[row][lane15 & ~1];
#pragma unroll
        for (int j = 0; j < 8; ++j) {
          const float pA = exp2f(sacc[i][j][rA]);
          const float pB = exp2f(sacc[i][j][rB]);
          lsum[i][rA] += pA;
          lsum[i][rB] += pB;
          const float an = __shfl_xor(pA, 1);
          const float bn = __shfl_xor(pB, 1);
          const float lo = odd ? bn : pA;
          const float hi = odd ? pB : an;
          *(unsigned int*)(prow + j * 16) = pack_h2(lo, hi);
        }
      }
    }

    // ---- O += P V (P rows wave-private; in-wave lgkmcnt suffices) ----
#pragma unroll
    for (int kc = 0; kc < 4; ++kc) {
      half8 pa0 = *(const half8*)&Ps[w * 32 + lane15][kc * 32 + quad * 8];
      half8 pa1 = *(const half8*)&Ps[w * 32 + 16 + lane15][kc * 32 + quad * 8];
#pragma unroll
      for (int dj = 0; dj < 4; ++dj) {
        const int drow = dj * 16 + lane15;
        half8 vf = *(const half8*)(
            Vs + drow * 128 + (((kc * 4 + quad) ^ (drow & 15)) << 3));
        oacc[0][dj] = __builtin_amdgcn_mfma_f32_16x16x32_f16(pa0, vf,
                                                             oacc[0][dj], 0, 0, 0);
        oacc[1][dj] = __builtin_amdgcn_mfma_f32_16x16x32_f16(pa1, vf,
                                                             oacc[1][dj], 0, 0, 0);
      }
    }
  }

  // ---- epilogue: butterfly l, normalize, pair-pack 4B stores ----
  float invl[2][4];
#pragma unroll
  for (int i = 0; i < 2; ++i)
#pragma unroll
    for (int r = 0; r < 4; ++r) {
      float ls = lsum[i][r];
#pragma unroll
      for (int off = 1; off < 16; off <<= 1) ls += __shfl_xor(ls, off);
      invl[i][r] = 1.f / ls;
    }
  const int br = bh >> 4, h = bh & 15;
  const size_t mbase = (size_t)br * 512 + qb + w * 32;
#pragma unroll
  for (int i = 0; i < 2; ++i)
#pragma unroll
    for (int dj = 0; dj < 4; ++dj) {
      const int e = h * 64 + dj * 16 + lane15;
      const int ee = e & ~1;
#pragma unroll
      for (int rp = 0; rp < 2; ++rp) {
        const int rA = 2 * rp, rB = rA + 1;
        float a = oacc[i][dj][rA] * invl[i][rA];
        float b = oacc[i][dj][rB] * invl[i][rB];
        float ax = __shfl_xor(a, 1), bx = __shfl_xor(b, 1);
        unsigned int u = odd ? pack_h2(bx, b) : pack_h2(a, ax);
        const size_t m = mbase + i * 16 + quad * 4 + rA + (odd ? 1 : 0);
        *(unsigned int*)(Ctx + m * 1024 + ee) = u;
      }
    }
}

// ---------------- launch ----------------
extern "C" void kernel_launch(void* const* d_in, const int* in_sizes, int n_in,
                              void* d_out, int out_size, void* d_ws,
                              size_t ws_size, hipStream_t stream) {
  const float* x = (const float*)d_in[0];
  const float* wq = (const float*)d_in[1];
  const float* bq = (const float*)d_in[2];
  const float* wk = (const float*)d_in[3];
  const float* bk = (const float*)d_in[4];
  const float* wv = (const float*)d_in[5];
  const float* bv = (const float*)d_in[6];
  const float* wo = (const float*)d_in[7];
  const float* bo = (const float*)d_in[8];
  float* out = (float*)d_out;

  char* w = (char*)d_ws;
  const size_t MiB = 1ull << 20;
  unsigned short* qbuf = (unsigned short*)(w + 0 * MiB);   // 32 MiB fp16
  unsigned short* kbuf = (unsigned short*)(w + 32 * MiB);  // 32 MiB
  unsigned short* vtb = (unsigned short*)(w + 64 * MiB);   // 32 MiB
  unsigned short* xh = (unsigned short*)(w + 96 * MiB);    // 32 MiB
  unsigned short* ctx = (unsigned short*)(w + 128 * MiB);  // 32 MiB
  unsigned short* wqh = (unsigned short*)(w + 160 * MiB);  // 2 MiB each,
  unsigned short* wkh = (unsigned short*)(w + 162 * MiB);  // contiguous ->
  unsigned short* wvh = (unsigned short*)(w + 164 * MiB);  // fused N=3072
  unsigned short* woh = (unsigned short*)(w + 166 * MiB);

  cvt_x<<<8192, 256, 0, stream>>>(x, xh);
  wprep<<<dim3(16, 16, 4), 256, 0, stream>>>(wq, wk, wv, wo, wqh, wkh, wvh,
                                             woh);

  // fused QKV projection: [16384,1024] x [1024,3072] over contiguous weights
  gemm256<0><<<768, 512, 0, stream>>>(xh, wqh, bq, bk, bv, qbuf, kbuf, vtb,
                                      nullptr, nullptr);

  attn_mfma<<<2048, 256, 0, stream>>>(qbuf, kbuf, vtb, ctx);

  gemm256<1><<<256, 512, 0, stream>>>(ctx, woh, nullptr, nullptr, nullptr,
                                      nullptr, nullptr, nullptr, out, bo);
}

// Round 2
// 387.482 us; speedup vs baseline: 1.0330x; 1.0283x over previous
//
#include <hip/hip_runtime.h>
#include <hip/hip_bf16.h>
#include <hip/hip_fp16.h>
#include <math.h>

typedef _Float16 half8 __attribute__((ext_vector_type(8)));
typedef __attribute__((ext_vector_type(4))) float floatx4;

constexpr int Bc = 2, Rc = 16, Cc = 512, Ec = 1024, Hc = 16, Dc = 64;
// fold 1/sqrt(64) * log2(e) into Q so softmax uses exp2 (v_exp_f32 native)
#define QSCALE 0.180336880111120425f

__device__ inline void gl_lds16(const void* g, void* l) {
  __builtin_amdgcn_global_load_lds(
      (const __attribute__((address_space(1))) void*)g,
      (__attribute__((address_space(3))) void*)l, 16, 0, 0);
}
__device__ inline unsigned short f2h(float f) {
  __half h = __float2half_rn(f);
  return *(unsigned short*)&h;
}
__device__ inline unsigned int pack_h2(float lo, float hi) {
  __half2 p = __float22half2_rn(make_float2(lo, hi));
  return *(unsigned int*)&p;
}

// ---------- x fp32 -> fp16 ----------
__global__ __launch_bounds__(256) void cvt_x(const float* __restrict__ x,
                                             unsigned short* __restrict__ xh) {
  const size_t base = ((size_t)blockIdx.x * 256 + threadIdx.x) * 8;
  float4 a = *(const float4*)(x + base);
  float4 b = *(const float4*)(x + base + 4);
  uint4 o;
  o.x = pack_h2(a.x, a.y);
  o.y = pack_h2(a.z, a.w);
  o.z = pack_h2(b.x, b.y);
  o.w = pack_h2(b.z, b.w);
  *(uint4*)(xh + base) = o;
}

// ---------- W[k][n] fp32 -> Wt[n][k] fp16 (transpose), z picks weight ------
__global__ __launch_bounds__(256) void wprep(
    const float* __restrict__ w0, const float* __restrict__ w1,
    const float* __restrict__ w2, const float* __restrict__ w3,
    unsigned short* __restrict__ t0, unsigned short* __restrict__ t1,
    unsigned short* __restrict__ t2, unsigned short* __restrict__ t3) {
  __shared__ float tile[64][65];
  const int z = blockIdx.z;
  const float* W = (z == 0) ? w0 : (z == 1) ? w1 : (z == 2) ? w2 : w3;
  unsigned short* T = (z == 0) ? t0 : (z == 1) ? t1 : (z == 2) ? t2 : t3;
  const int tid = threadIdx.x;
  const int bk = blockIdx.x * 64, bn = blockIdx.y * 64;
#pragma unroll
  for (int p = 0; p < 16; ++p) {
    int idx = p * 256 + tid;
    int lk = idx >> 6, ln = idx & 63;
    tile[ln][lk] = W[(size_t)(bk + lk) * 1024 + bn + ln];
  }
  __syncthreads();
#pragma unroll
  for (int p = 0; p < 16; ++p) {
    int idx = p * 256 + tid;
    int ln = idx >> 6, lk = idx & 63;
    T[(size_t)(bn + ln) * 1024 + bk + lk] = f2h(tile[ln][lk]);
  }
}

// ===========================================================================
// 256x256 BK=64 double-buffered 4-phase GEMM, deep counted-vmcnt pipeline.
// Staging units match LDS read footprints exactly (one read-phase per unit):
//   A unit MH = rows {MH*64..+63} u {128+MH*64..+63}  (read by DSRA(MH) only)
//   B unit NH = rows {b*64+NH*32..+31 : b<4}          (read by DSRB(NH) only)
// Quadrant order (0,0),(0,1),(1,0),(1,1); af held 2 phases, bf0/bf1 whole
// tile -> 24 ds_read_b128/wave/tile (minimal). Stage plan for tile T+2
// (into current buf, regions freed one phase earlier):
//   P2: A0+B0 (4 ld/wave)   P3: B1 (2)   P4: A1 (2)
// stage->read distance = 7 phases. One wait/tile: vmcnt(8) at P4 (own 8
// stage-instrs in flight; tile T+1 guaranteed landed). Never vmcnt(0)
// mid-loop. LDS swizzle: chunk ^= (row&7), imposed via inverse-permuted
// global source (linear gl_lds dest), undone at ds_read. 2-way banks free.
// ===========================================================================
#define STG_A(BUF, KT, MH)                                                    \
  {                                                                           \
    _Pragma("unroll") for (int l_ = 0; l_ < 2; ++l_) {                        \
      const int r0_ = l_ * 128 + (MH) * 64 + w * 8;                           \
      gl_lds16(Ab + (size_t)r0_ * 1024 + (size_t)(KT) * 64 + goff,            \
               As + (BUF) * 16384 + r0_ * 64);                                \
    }                                                                         \
  }

#define STG_B(BUF, KT, NH)                                                    \
  {                                                                           \
    _Pragma("unroll") for (int l_ = 0; l_ < 2; ++l_) {                        \
      const int r0_ = (w >> 1) * 64 + (NH) * 32 + ((w & 1) * 2 + l_) * 8;     \
      gl_lds16(Bb + (size_t)r0_ * 1024 + (size_t)(KT) * 64 + goff,            \
               Bs + (BUF) * 16384 + r0_ * 64);                                \
    }                                                                         \
  }

#define DSRA(BUF, MH)                                                         \
  _Pragma("unroll") for (int i_ = 0; i_ < 4; ++i_) {                          \
    const unsigned short* p_ =                                                \
        As + (BUF) * 16384 + (wm + (MH) * 64 + i_ * 16 + lr) * 64;            \
    af[i_][0] = *(const half8*)(p_ + sw0);                                    \
    af[i_][1] = *(const half8*)(p_ + sw1);                                    \
  }

#define DSRB(BUF, NH, DST)                                                    \
  _Pragma("unroll") for (int j_ = 0; j_ < 2; ++j_) {                          \
    const unsigned short* p_ =                                                \
        Bs + (BUF) * 16384 + (wn + (NH) * 32 + j_ * 16 + lr) * 64;            \
    DST[j_][0] = *(const half8*)(p_ + sw0);                                   \
    DST[j_][1] = *(const half8*)(p_ + sw1);                                   \
  }

#define MFMA16(MH, NH, BF)                                                    \
  _Pragma("unroll") for (int i_ = 0; i_ < 4; ++i_)                            \
      _Pragma("unroll") for (int j_ = 0; j_ < 2; ++j_) {                      \
    acc[(MH)*4 + i_][(NH)*2 + j_] = __builtin_amdgcn_mfma_f32_16x16x32_f16(   \
        af[i_][0], BF[j_][0], acc[(MH)*4 + i_][(NH)*2 + j_], 0, 0, 0);        \
    acc[(MH)*4 + i_][(NH)*2 + j_] = __builtin_amdgcn_mfma_f32_16x16x32_f16(   \
        af[i_][1], BF[j_][1], acc[(MH)*4 + i_][(NH)*2 + j_], 0, 0, 0);        \
  }

#define WAIT_LGKM0                                                            \
  {                                                                           \
    asm volatile("s_waitcnt lgkmcnt(0)" ::: "memory");                        \
    __builtin_amdgcn_sched_barrier(0);                                        \
  }
#define WAIT_VM(N)                                                            \
  {                                                                           \
    asm volatile("s_waitcnt vmcnt(" #N ")" ::: "memory");                     \
    __builtin_amdgcn_sched_barrier(0);                                        \
  }

// ENDW: 0 = steady vmcnt(8); 1 = drain vmcnt(0); 2 = no wait (last tile)
#define TILE(T, BUF, STAGE, ENDW)                                             \
  {                                                                           \
    /* P1: read A0->af, B0->bf0 */                                            \
    DSRA(BUF, 0);                                                             \
    DSRB(BUF, 0, bf0);                                                        \
    __builtin_amdgcn_s_barrier();                                             \
    WAIT_LGKM0;                                                               \
    __builtin_amdgcn_s_setprio(1);                                            \
    MFMA16(0, 0, bf0);                                                        \
    __builtin_amdgcn_s_setprio(0);                                            \
    __builtin_amdgcn_s_barrier();                                             \
    __builtin_amdgcn_sched_barrier(0);                                        \
    /* P2: read B1->bf1; stage (T+2).A0,(T+2).B0 */                           \
    DSRB(BUF, 1, bf1);                                                        \
    if (STAGE) {                                                              \
      STG_A(BUF, (T) + 2, 0);                                                 \
      STG_B(BUF, (T) + 2, 0);                                                 \
    }                                                                         \
    __builtin_amdgcn_s_barrier();                                             \
    WAIT_LGKM0;                                                               \
    __builtin_amdgcn_s_setprio(1);                                            \
    MFMA16(0, 1, bf1);                                                        \
    __builtin_amdgcn_s_setprio(0);                                            \
    __builtin_amdgcn_s_barrier();                                             \
    __builtin_amdgcn_sched_barrier(0);                                        \
    /* P3: read A1->af; stage (T+2).B1 */                                     \
    DSRA(BUF, 1);                                                             \
    if (STAGE) { STG_B(BUF, (T) + 2, 1); }                                    \
    __builtin_amdgcn_s_barrier();                                             \
    WAIT_LGKM0;                                                               \
    __builtin_amdgcn_s_setprio(1);                                            \
    MFMA16(1, 0, bf0);                                                        \
    __builtin_amdgcn_s_setprio(0);                                            \
    __builtin_amdgcn_s_barrier();                                             \
    __builtin_amdgcn_sched_barrier(0);                                        \
    /* P4: stage (T+2).A1; pure-reg MFMA; counted wait; barrier */            \
    if (STAGE) { STG_A(BUF, (T) + 2, 1); }                                    \
    __builtin_amdgcn_s_setprio(1);                                            \
    MFMA16(1, 1, bf1);                                                        \
    __builtin_amdgcn_s_setprio(0);                                            \
    if (ENDW == 0) {                                                          \
      WAIT_VM(8);                                                             \
    } else if (ENDW == 1) {                                                   \
      WAIT_VM(0);                                                             \
    }                                                                         \
    __builtin_amdgcn_s_barrier();                                             \
    __builtin_amdgcn_sched_barrier(0);                                        \
  }

template <int MODE>
__global__ __launch_bounds__(512, 2) void gemm256(
    const unsigned short* __restrict__ gA, const unsigned short* __restrict__ gB,
    const float* __restrict__ bq, const float* __restrict__ bk,
    const float* __restrict__ bv, unsigned short* __restrict__ qout,
    unsigned short* __restrict__ kout, unsigned short* __restrict__ vout,
    float* __restrict__ fout, const float* __restrict__ bo) {
  __shared__ unsigned short As[2 * 16384];  // 64 KB (2 buf x 256 x 64)
  __shared__ unsigned short Bs[2 * 16384];  // 64 KB
  const int tid = threadIdx.x;
  const int w = tid >> 6, ln = tid & 63;
  const int lr = ln & 15, quad = ln >> 4;
  const int wm = (w >> 2) * 128, wn = (w & 3) * 64;
  int bm, bn;
  if (MODE == 0) {
    const int swz = (blockIdx.x & 7) * 96 + (blockIdx.x >> 3);  // 768 wgs
    bm = (swz / 12) * 256;
    bn = (swz % 12) * 256;
  } else {
    const int swz = (blockIdx.x & 7) * 32 + (blockIdx.x >> 3);  // 256 wgs
    bm = (swz >> 2) * 256;
    bn = (swz & 3) * 256;
  }
  const unsigned short* Ab = gA + (size_t)bm * 1024;
  const unsigned short* Bb = gB + (size_t)bn * 1024;
  // per-lane staging offset: row = base + (ln>>3), src chunk = (ln&7)^(ln>>3)
  const int goff = (ln >> 3) * 1024 + (((ln & 7) ^ (ln >> 3)) << 3);
  // ds_read swizzled chunk offsets (K halves): chunk = (kk*4|quad) ^ (row&7)
  const int sw0 = ((quad ^ (lr & 7)) << 3);
  const int sw1 = (((4 | quad) ^ (lr & 7)) << 3);

  floatx4 acc[8][4];
#pragma unroll
  for (int i = 0; i < 8; ++i)
#pragma unroll
    for (int j = 0; j < 4; ++j) acc[i][j] = (floatx4)(0.f);
  half8 af[4][2], bf0[2][2], bf1[2][2];

  // prologue: stage tiles 0 and 1 fully; allow tile1's 8 loads in flight
  STG_A(0, 0, 0);
  STG_A(0, 0, 1);
  STG_B(0, 0, 0);
  STG_B(0, 0, 1);
  STG_A(1, 1, 0);
  STG_A(1, 1, 1);
  STG_B(1, 1, 0);
  STG_B(1, 1, 1);
  WAIT_VM(8);
  __builtin_amdgcn_s_barrier();
  __builtin_amdgcn_sched_barrier(0);

  for (int t = 0; t < 7; ++t) {  // tiles 0..13, staging tiles 2..15
    TILE(2 * t, 0, 1, 0);
    TILE(2 * t + 1, 1, 1, 0);
  }
  TILE(14, 0, 0, 1);  // drain: tile15 fully landed
  TILE(15, 1, 0, 2);  // no stages, no wait

  // ----- epilogue -----
  const int q4 = quad * 4;
  const bool odd = ln & 1;
  if constexpr (MODE == 0) {
    const int z = bn >> 10;  // block-uniform (BN=256 divides 1024)
    const float* bias = (z == 0) ? bq : (z == 1) ? bk : bv;
    const int czb = (bn & 1023) + wn;
#pragma unroll
    for (int i = 0; i < 8; ++i) {
#pragma unroll
      for (int j = 0; j < 4; ++j) {
        const int colz = czb + j * 16 + lr;
        float v[4];
#pragma unroll
        for (int r = 0; r < 4; ++r) v[r] = acc[i][j][r] + bias[colz];
        const int m0 = bm + wm + i * 16 + q4;
        const int h = colz >> 6, d = colz & 63;
        const int brr = m0 >> 9, c0 = m0 & 511;
        const size_t hb = ((size_t)brr * 16 + h) * 32768;
        if (z == 2) {
          // V^T [d][c]: 4 consecutive c per thread -> one 8B store
          uint2 o;
          o.x = pack_h2(v[0], v[1]);
          o.y = pack_h2(v[2], v[3]);
          *(uint2*)(vout + hb + (size_t)d * 512 + c0) = o;
        } else {
          unsigned short* outp = (z == 0) ? qout : kout;
          if (z == 0) {
#pragma unroll
            for (int r = 0; r < 4; ++r) v[r] *= QSCALE;
          }
          // [c][d]: lane-pair exchange -> 4B stores
#pragma unroll
          for (int rp = 0; rp < 2; ++rp) {
            float a = v[2 * rp], b = v[2 * rp + 1];
            float ax = __shfl_xor(a, 1), bx = __shfl_xor(b, 1);
            unsigned int u = odd ? pack_h2(bx, b) : pack_h2(a, ax);
            const int c = c0 + 2 * rp + (odd ? 1 : 0);
            const int dd = d & ~1;
            *(unsigned int*)(outp + hb + (size_t)c * 64 + dd) = u;
          }
        }
      }
    }
  } else {
#pragma unroll
    for (int i = 0; i < 8; ++i)
#pragma unroll
      for (int j = 0; j < 4; ++j) {
        const int col = bn + wn + j * 16 + lr;
#pragma unroll
        for (int r = 0; r < 4; ++r) {
          const int m = bm + wm + i * 16 + q4 + r;
          fout[(size_t)m * 1024 + col] = acc[i][j][r] + bo[col];
        }
      }
  }
}

// ---------- MFMA flash attention, fp16 (no-max softmax: logits small) ------
// Q fp16 [bh][c][d] (pre-scaled); K fp16 [bh][c][d]; Vt fp16 [bh][d][c].
// Out: ctx fp16 [m][e]. 256 thr, one (bh, 128q tile); wave owns 32 q.
__global__ __launch_bounds__(256, 2) void attn_mfma(
    const unsigned short* __restrict__ Qh, const unsigned short* __restrict__ Kb,
    const unsigned short* __restrict__ Vt, unsigned short* __restrict__ Ctx) {
  __shared__ unsigned short Ks[128 * 64];   // [k][d], slot-swizzle c16^=(k&7)
  __shared__ unsigned short Vs[64 * 128];   // [d][k], slot-swizzle c16^=(d&15)
  __shared__ unsigned short Ps[128][136];   // [q][k] fp16, +8 pad

  const int t = threadIdx.x;
  const int w = t >> 6, ln = t & 63;
  const int lane15 = ln & 15, quad = ln >> 4;
  const bool odd = ln & 1;
  const int bh = blockIdx.x >> 2;
  const int qb = (blockIdx.x & 3) * 128;

  half8 qf[2][2];
  {
    const size_t qbase =
        ((size_t)bh * 512 + qb + w * 32 + lane15) * 64 + quad * 8;
#pragma unroll
    for (int i = 0; i < 2; ++i)
#pragma unroll
      for (int c = 0; c < 2; ++c)
        qf[i][c] = *(const half8*)(Qh + qbase + (size_t)i * 16 * 64 + c * 32);
  }

  floatx4 oacc[2][4];
#pragma unroll
  for (int i = 0; i < 2; ++i)
#pragma unroll
    for (int dj = 0; dj < 4; ++dj) oacc[i][dj] = (floatx4)(0.f);
  float lsum[2][4];
#pragma unroll
  for (int i = 0; i < 2; ++i)
#pragma unroll
    for (int r = 0; r < 4; ++r) lsum[i][r] = 0.f;

  const unsigned short* kgb = Kb + (size_t)bh * 32768;
  const unsigned short* vgb = Vt + (size_t)bh * 32768;

  for (int kt = 0; kt < 512; kt += 128) {
    __syncthreads();
    {
      const unsigned short* kq = kgb + (size_t)kt * 64;
#pragma unroll
      for (int p = 0; p < 4; ++p) {
        const int s = p * 256 + t;
        const int kr = s >> 3, kc16 = s & 7;
        gl_lds16(kq + kr * 64 + ((kc16 ^ (kr & 7)) << 3), (char*)Ks + s * 16);
        const int vr = s >> 4, vc16 = s & 15;
        gl_lds16(vgb + vr * 512 + kt + ((vc16 ^ (vr & 15)) << 3),
                 (char*)Vs + s * 16);
      }
    }
    __syncthreads();

    // ---- S = Q K^T ----
    floatx4 sacc[2][8];
#pragma unroll
    for (int i = 0; i < 2; ++i)
#pragma unroll
      for (int j = 0; j < 8; ++j) sacc[i][j] = (floatx4)(0.f);
#pragma unroll
    for (int j = 0; j < 8; ++j) {
      const int krow = j * 16 + lane15;
      const unsigned short* kr = Ks + krow * 64;
      half8 kf0 = *(const half8*)(kr + ((quad ^ (krow & 7)) << 3));
      half8 kf1 = *(const half8*)(kr + (((4 + quad) ^ (krow & 7)) << 3));
#pragma unroll
      for (int i = 0; i < 2; ++i) {
        sacc[i][j] = __builtin_amdgcn_mfma_f32_16x16x32_f16(qf[i][0], kf0,
                                                            sacc[i][j], 0, 0, 0);
        sacc[i][j] = __builtin_amdgcn_mfma_f32_16x16x32_f16(qf[i][1], kf1,
                                                            sacc[i][j], 0, 0, 0);
      }
    }

    // ---- P = exp2(S) (no max-sub: |S| small), pack pairs, write P[q][k] ---
#pragma unroll
    for (int i = 0; i < 2; ++i) {
#pragma unroll
      for (int rp = 0; rp < 2; ++rp) {
        const int rA = rp * 2, rB = rA + 1;
        const int row = w * 32 + i * 16 + quad * 4 + rA + (odd ? 1 : 0);
        unsigned short* prow = &Ps[row][lane15 & ~1];
#pragma unroll
        for (int j = 0; j < 8; ++j) {
          const float pA = exp2f(sacc[i][j][rA]);
          const float pB = exp2f(sacc[i][j][rB]);
          lsum[i][rA] += pA;
          lsum[i][rB] += pB;
          const float an = __shfl_xor(pA, 1);
          const float bn = __shfl_xor(pB, 1);
          const float lo = odd ? bn : pA;
          const float hi = odd ? pB : an;
          *(unsigned int*)(prow + j * 16) = pack_h2(lo, hi);
        }
      }
    }

    // ---- O += P V (P rows wave-private; in-wave lgkmcnt suffices) ----
#pragma unroll
    for (int kc = 0; kc < 4; ++kc) {
      half8 pa0 = *(const half8*)&Ps[w * 32 + lane15][kc * 32 + quad * 8];
      half8 pa1 = *(const half8*)&Ps[w * 32 + 16 + lane15][kc * 32 + quad * 8];
#pragma unroll
      for (int dj = 0; dj < 4; ++dj) {
        const int drow = dj * 16 + lane15;
        half8 vf = *(const half8*)(
            Vs + drow * 128 + (((kc * 4 + quad) ^ (drow & 15)) << 3));
        oacc[0][dj] = __builtin_amdgcn_mfma_f32_16x16x32_f16(pa0, vf,
                                                             oacc[0][dj], 0, 0, 0);
        oacc[1][dj] = __builtin_amdgcn_mfma_f32_16x16x32_f16(pa1, vf,
                                                             oacc[1][dj], 0, 0, 0);
      }
    }
  }

  // ---- epilogue: butterfly l, normalize, pair-pack 4B stores ----
  float invl[2][4];
#pragma unroll
  for (int i = 0; i < 2; ++i)
#pragma unroll
    for (int r = 0; r < 4; ++r) {
      float ls = lsum[i][r];
#pragma unroll
      for (int off = 1; off < 16; off <<= 1) ls += __shfl_xor(ls, off);
      invl[i][r] = 1.f / ls;
    }
  const int br = bh >> 4, h = bh & 15;
  const size_t mbase = (size_t)br * 512 + qb + w * 32;
#pragma unroll
  for (int i = 0; i < 2; ++i)
#pragma unroll
    for (int dj = 0; dj < 4; ++dj) {
      const int e = h * 64 + dj * 16 + lane15;
      const int ee = e & ~1;
#pragma unroll
      for (int rp = 0; rp < 2; ++rp) {
        const int rA = 2 * rp, rB = rA + 1;
        float a = oacc[i][dj][rA] * invl[i][rA];
        float b = oacc[i][dj][rB] * invl[i][rB];
        float ax = __shfl_xor(a, 1), bx = __shfl_xor(b, 1);
        unsigned int u = odd ? pack_h2(bx, b) : pack_h2(a, ax);
        const size_t m = mbase + i * 16 + quad * 4 + rA + (odd ? 1 : 0);
        *(unsigned int*)(Ctx + m * 1024 + ee) = u;
      }
    }
}

// ---------------- launch ----------------
extern "C" void kernel_launch(void* const* d_in, const int* in_sizes, int n_in,
                              void* d_out, int out_size, void* d_ws,
                              size_t ws_size, hipStream_t stream) {
  const float* x = (const float*)d_in[0];
  const float* wq = (const float*)d_in[1];
  const float* bq = (const float*)d_in[2];
  const float* wk = (const float*)d_in[3];
  const float* bk = (const float*)d_in[4];
  const float* wv = (const float*)d_in[5];
  const float* bv = (const float*)d_in[6];
  const float* wo = (const float*)d_in[7];
  const float* bo = (const float*)d_in[8];
  float* out = (float*)d_out;

  char* w = (char*)d_ws;
  const size_t MiB = 1ull << 20;
  unsigned short* qbuf = (unsigned short*)(w + 0 * MiB);   // 32 MiB fp16
  unsigned short* kbuf = (unsigned short*)(w + 32 * MiB);  // 32 MiB
  unsigned short* vtb = (unsigned short*)(w + 64 * MiB);   // 32 MiB
  unsigned short* xh = (unsigned short*)(w + 96 * MiB);    // 32 MiB
  unsigned short* ctx = (unsigned short*)(w + 128 * MiB);  // 32 MiB
  unsigned short* wqh = (unsigned short*)(w + 160 * MiB);  // 2 MiB each,
  unsigned short* wkh = (unsigned short*)(w + 162 * MiB);  // contiguous ->
  unsigned short* wvh = (unsigned short*)(w + 164 * MiB);  // fused N=3072
  unsigned short* woh = (unsigned short*)(w + 166 * MiB);

  cvt_x<<<8192, 256, 0, stream>>>(x, xh);
  wprep<<<dim3(16, 16, 4), 256, 0, stream>>>(wq, wk, wv, wo, wqh, wkh, wvh,
                                             woh);

  // fused QKV projection: [16384,1024] x [1024,3072] over contiguous weights
  gemm256<0><<<768, 512, 0, stream>>>(xh, wqh, bq, bk, bv, qbuf, kbuf, vtb,
                                      nullptr, nullptr);

  attn_mfma<<<2048, 256, 0, stream>>>(qbuf, kbuf, vtb, ctx);

  gemm256<1><<<256, 512, 0, stream>>>(ctx, woh, nullptr, nullptr, nullptr,
                                      nullptr, nullptr, nullptr, out, bo);
}